// Round 14
// baseline (156.421 us; speedup 1.0000x reference)
//
#include <hip/hip_runtime.h>
#include <hip/hip_fp16.h>

// Boids ODE segment-sum v10 (resubmit after infra failure): v9 (u64 fixed-point
// LDS atomics in accum) with scatter LDS halved (SEPB 8192->4096: 56KB->32KB
// per block -> 2->5 blocks/CU). Round-12 profile: scatter 55us @ 15% occupancy,
// latency-bound; more resident waves + half the serial chain should cut it ~2x.

#define BA1 5e-06f
#define BA2 0.0005f
#define BA3 1e-08f

#define NT 256        // threads per block
#define NWAVE 4       // NT/64
#define CEPB 4096     // edges per count block
#define SEPB 4096     // edges per scatter block (32KB LDS -> 5 blocks/CU)
#define WIN 256       // receiver nodes per bucket
#define WSH 8         // log2(WIN)
#define SPLIT 8       // accum blocks per bucket
#define NBMAX 512     // max buckets
#define FPS 4194304.f // fixed-point scale 2^22

// ---------------- K1: fused pack + count ----------------
__global__ void __launch_bounds__(NT)
k_prep(const float* __restrict__ pos, const float* __restrict__ vel,
       const float* __restrict__ field, const int* __restrict__ dst,
       int N, int E, int NB, int NCBLK,
       float4* __restrict__ rec16, unsigned* __restrict__ cnt) {
    int bx = blockIdx.x, tid = threadIdx.x;
    if (bx < NCBLK) {
        __shared__ unsigned hist[NBMAX];
        for (int b = tid; b < NBMAX; b += NT) hist[b] = 0u;
        __syncthreads();
        int s = bx * CEPB, e = min(E, s + CEPB);
        int k = s + 4 * tid;
        for (; k + 3 < e; k += 4 * NT) {
            int4 d = *reinterpret_cast<const int4*>(dst + k);
            atomicAdd(&hist[d.x >> WSH], 1u);
            atomicAdd(&hist[d.y >> WSH], 1u);
            atomicAdd(&hist[d.z >> WSH], 1u);
            atomicAdd(&hist[d.w >> WSH], 1u);
        }
        int rem = (e - s) & 3;
        if (tid < rem) atomicAdd(&hist[dst[e - rem + tid] >> WSH], 1u);
        __syncthreads();
        for (int b = tid; b < NB; b += NT)
            if (hist[b]) atomicAdd(&cnt[b], hist[b]);
    } else {
        int i = (bx - NCBLK) * NT + tid;
        if (i >= N) return;
        float2 p = *reinterpret_cast<const float2*>(pos + 2 * i);
        float2 v = *reinterpret_cast<const float2*>(vel + 2 * i);
        unsigned short sx = __half_as_ushort(__float2half(v.x));
        unsigned short sy = __half_as_ushort(__float2half(v.y));
        unsigned pv = (unsigned)sx | ((unsigned)sy << 16);
        rec16[i] = make_float4(p.x, p.y, __uint_as_float(pv), field[i]);
    }
}

// ---------------- K2: single-block scan of bucket totals ----------------
__global__ void __launch_bounds__(NT)
k_scanb(const unsigned* __restrict__ cnt, unsigned* __restrict__ base,
        unsigned* __restrict__ cursor, int NB) {
    __shared__ unsigned t[NBMAX];
    __shared__ unsigned sz[NBMAX];
    int tid = threadIdx.x;
    for (int i = tid; i < NBMAX; i += NT) {
        unsigned c = (i < NB) ? cnt[i] : 0u;
        sz[i] = (c + 3u) & ~3u;
        t[i] = sz[i];
    }
    __syncthreads();
    for (int o = 1; o < NBMAX; o <<= 1) {
        unsigned v0 = (tid >= o) ? t[tid - o] : 0u;
        unsigned v1 = (tid + NT >= o) ? t[tid + NT - o] : 0u;
        __syncthreads();
        t[tid] += v0;
        t[tid + NT] += v1;
        __syncthreads();
    }
    for (int i = tid; i < NB; i += NT) {
        unsigned b = t[i] - sz[i];
        base[i] = b;
        cursor[i] = b;
    }
}

// ---------------- K3: multisplit scatter ----------------
__global__ void __launch_bounds__(NT)
k_scatter(const int* __restrict__ dst, const int* __restrict__ src,
          int E, int NB,
          unsigned* __restrict__ cursor,
          unsigned* __restrict__ pk) {
    __shared__ unsigned lh[NBMAX];
    __shared__ unsigned lofs[NBMAX];
    __shared__ unsigned lcur[NBMAX];
    __shared__ unsigned gbase[NBMAX];
    __shared__ unsigned sbuf[SEPB];
    __shared__ unsigned short sbkt[SEPB];
    int blk = blockIdx.x, tid = threadIdx.x;
    int s = blk * SEPB, e = min(E, s + SEPB);

    for (int b = tid; b < NBMAX; b += NT) lh[b] = 0u;
    __syncthreads();

    int k = s + 4 * tid;
    for (; k + 3 < e; k += 4 * NT) {
        int4 d = *reinterpret_cast<const int4*>(dst + k);
        atomicAdd(&lh[d.x >> WSH], 1u);
        atomicAdd(&lh[d.y >> WSH], 1u);
        atomicAdd(&lh[d.z >> WSH], 1u);
        atomicAdd(&lh[d.w >> WSH], 1u);
    }
    {
        int rem = (e - s) & 3;
        if (tid < rem) atomicAdd(&lh[dst[e - rem + tid] >> WSH], 1u);
    }
    __syncthreads();
    for (int b = tid; b < NBMAX; b += NT) lofs[b] = lh[b];
    __syncthreads();

    for (int o = 1; o < NBMAX; o <<= 1) {
        unsigned v0 = (tid >= o) ? lh[tid - o] : 0u;
        unsigned v1 = (tid + NT >= o) ? lh[tid + NT - o] : 0u;
        __syncthreads();
        lh[tid] += v0;
        lh[tid + NT] += v1;
        __syncthreads();
    }
    for (int b = tid; b < NBMAX; b += NT) {
        unsigned c = lofs[b];
        unsigned ex = lh[b] - c;
        lofs[b] = ex;
        lcur[b] = ex;
        if (b < NB && c > 0u) gbase[b] = atomicAdd(&cursor[b], c);
    }
    __syncthreads();

    k = s + 4 * tid;
    for (; k + 3 < e; k += 4 * NT) {
        int4 d = *reinterpret_cast<const int4*>(dst + k);
        int4 j = *reinterpret_cast<const int4*>(src + k);
        int b0 = d.x >> WSH; unsigned r0 = atomicAdd(&lcur[b0], 1u);
        sbuf[r0] = ((unsigned)(d.x & (WIN - 1)) << 24) | (unsigned)j.x; sbkt[r0] = (unsigned short)b0;
        int b1 = d.y >> WSH; unsigned r1 = atomicAdd(&lcur[b1], 1u);
        sbuf[r1] = ((unsigned)(d.y & (WIN - 1)) << 24) | (unsigned)j.y; sbkt[r1] = (unsigned short)b1;
        int b2 = d.z >> WSH; unsigned r2 = atomicAdd(&lcur[b2], 1u);
        sbuf[r2] = ((unsigned)(d.z & (WIN - 1)) << 24) | (unsigned)j.z; sbkt[r2] = (unsigned short)b2;
        int b3 = d.w >> WSH; unsigned r3 = atomicAdd(&lcur[b3], 1u);
        sbuf[r3] = ((unsigned)(d.w & (WIN - 1)) << 24) | (unsigned)j.w; sbkt[r3] = (unsigned short)b3;
    }
    {
        int rem = (e - s) & 3;
        if (tid < rem) {
            int kk = e - rem + tid;
            int d = dst[kk];
            int b = d >> WSH; unsigned r = atomicAdd(&lcur[b], 1u);
            sbuf[r] = ((unsigned)(d & (WIN - 1)) << 24) | (unsigned)src[kk]; sbkt[r] = (unsigned short)b;
        }
    }
    __syncthreads();

    int ne = e - s;
    for (int t = tid; t < ne; t += NT) {
        unsigned b = sbkt[t];
        pk[gbase[b] + ((unsigned)t - lofs[b])] = sbuf[t];
    }
}

// ---------------- K4: accumulate, ONE u64 integer LDS atomic per edge ----------
__global__ void __launch_bounds__(NT, 4)
k_accum(const float4* __restrict__ rec16,
        const float* __restrict__ p_table,
        const int* __restrict__ ptype,
        const unsigned* __restrict__ pk,
        const unsigned* __restrict__ base,
        const unsigned* __restrict__ cnt,
        int N,
        float* __restrict__ out) {
    __shared__ float4 wnode[WIN];                     // receiver {px,py,vx,vy}
    __shared__ float4 wcoef[WIN];                     // {c0*A1, c1*A2, c2*A3, 0}
    __shared__ unsigned long long acc64[NWAVE][WIN];  // per-wave packed {x:hi,y:lo}
    int b = blockIdx.x, tid = threadIdx.x;
    int bb = b << WSH;
    int wn = min(N - bb, WIN);
    int wv = tid >> 6;

    if (tid < wn) {
        int g = bb + tid;
        float4 r = rec16[g];
        unsigned u = __float_as_uint(r.z);
        float vx = __half2float(__ushort_as_half((unsigned short)(u & 0xFFFFu)));
        float vy = __half2float(__ushort_as_half((unsigned short)(u >> 16)));
        wnode[tid] = make_float4(r.x, r.y, vx, vy);
        int ty = ptype[g];
        wcoef[tid] = make_float4(p_table[3 * ty + 0] * BA1,
                                 p_table[3 * ty + 1] * BA2,
                                 p_table[3 * ty + 2] * BA3, 0.f);
    }
    {
        unsigned long long* a = &acc64[0][0];
        for (int t = tid; t < NWAVE * WIN; t += NT) a[t] = 0ull;
    }
    __syncthreads();

    unsigned s = base[b];
    unsigned c = cnt[b];
    unsigned e = s + c;

#define EDGE1(PV)                                                              \
    {                                                                          \
        unsigned p_ = (PV);                                                    \
        int l_ = (int)(p_ >> 24);                                              \
        int j_ = (int)(p_ & 0xFFFFFFu);                                        \
        float4 nj_ = rec16[j_];                                                \
        unsigned u_ = __float_as_uint(nj_.z);                                  \
        float vjx_ = __half2float(__ushort_as_half((unsigned short)(u_ & 0xFFFFu))); \
        float vjy_ = __half2float(__ushort_as_half((unsigned short)(u_ >> 16))); \
        float4 w_ = wnode[l_];                                                 \
        float4 c_ = wcoef[l_];                                                 \
        float dpx_ = nj_.x - w_.x, dpy_ = nj_.y - w_.y;                        \
        float dvx_ = vjx_ - w_.z, dvy_ = vjy_ - w_.w;                          \
        float d2_ = dpx_ * dpx_ + dpy_ * dpy_;                                 \
        float sd2_ = (d2_ > 0.f) ? d2_ : 1.f;                                  \
        float cdp_ = c_.x - c_.z / sd2_;                                       \
        float mx_ = (cdp_ * dpx_ + c_.y * dvx_) * nj_.w;                       \
        float my_ = (cdp_ * dpy_ + c_.y * dvy_) * nj_.w;                       \
        long long ax_ = (long long)(int)(mx_ * FPS);                           \
        long long ay_ = (long long)(int)(my_ * FPS);                           \
        atomicAdd(&acc64[wv][l_], (unsigned long long)((ax_ << 32) + ay_));    \
    }

    unsigned stride = (unsigned)NT * SPLIT * 4u;
    for (unsigned k0 = s + ((unsigned)blockIdx.y * NT + tid) * 4u;
         k0 + 4u <= e; k0 += stride) {
        uint4 a = *reinterpret_cast<const uint4*>(pk + k0);
        EDGE1(a.x); EDGE1(a.y); EDGE1(a.z); EDGE1(a.w);
    }
    unsigned tail = c & 3u;
    if (blockIdx.y == 0 && tid < (int)tail) EDGE1(pk[e - tail + tid]);
#undef EDGE1

    __syncthreads();
    // merge wave copies, decode fixed-point, accumulate into out
    for (int l = tid; l < wn; l += NT) {
        unsigned long long T = acc64[0][l] + acc64[1][l] +
                               acc64[2][l] + acc64[3][l];
        long long Ts = (long long)T;
        int yb = (int)(unsigned)(T & 0xFFFFFFFFull);   // signed lower sum
        long long rem = Ts - (long long)yb;            // exact multiple of 2^32
        int xb = (int)(rem >> 32);                     // signed upper sum
        atomicAdd(&out[2 * (bb + l) + 0], (float)xb * (1.f / FPS));
        atomicAdd(&out[2 * (bb + l) + 1], (float)yb * (1.f / FPS));
    }
}

// ---------------- fallback: baseline edge-parallel atomics ----------------
__global__ void boids_edge_kernel(const float* __restrict__ pos,
                                  const float* __restrict__ vel,
                                  const float* __restrict__ p_table,
                                  const float* __restrict__ field,
                                  const int* __restrict__ ptype,
                                  const int* __restrict__ dst_idx,
                                  const int* __restrict__ src_idx,
                                  float* __restrict__ out,
                                  int n_edges) {
    int e = blockIdx.x * blockDim.x + threadIdx.x;
    if (e >= n_edges) return;
    int i = dst_idx[e], j = src_idx[e];
    float2 pi = *reinterpret_cast<const float2*>(pos + 2 * i);
    float2 pj = *reinterpret_cast<const float2*>(pos + 2 * j);
    float2 vi = *reinterpret_cast<const float2*>(vel + 2 * i);
    float2 vj = *reinterpret_cast<const float2*>(vel + 2 * j);
    float dpx = pj.x - pi.x, dpy = pj.y - pi.y;
    float dvx = vj.x - vi.x, dvy = vj.y - vi.y;
    int t = ptype[i];
    float p0 = p_table[3 * t + 0], p1 = p_table[3 * t + 1], p2 = p_table[3 * t + 2];
    float d2 = dpx * dpx + dpy * dpy;
    float sd2 = (d2 > 0.0f) ? d2 : 1.0f;
    float cdp = p0 * BA1 - p2 * BA3 / sd2;
    float cdv = p1 * BA2;
    float f = field[j];
    atomicAdd(&out[2 * i + 0], (cdp * dpx + cdv * dvx) * f);
    atomicAdd(&out[2 * i + 1], (cdp * dpy + cdv * dvy) * f);
}

extern "C" void kernel_launch(void* const* d_in, const int* in_sizes, int n_in,
                              void* d_out, int out_size, void* d_ws, size_t ws_size,
                              hipStream_t stream) {
    const float* pos     = (const float*)d_in[0];   // [N,2]
    const float* vel     = (const float*)d_in[1];   // [N,2]
    const float* p_table = (const float*)d_in[2];   // [16,3]
    const float* field   = (const float*)d_in[3];   // [N,1]
    const int*   ptype   = (const int*)d_in[4];     // [N]
    const int*   eidx    = (const int*)d_in[5];     // [2,E]

    int N = in_sizes[0] / 2;
    int E = in_sizes[5] / 2;
    const int* dstI = eidx;
    const int* srcI = eidx + E;
    float* out = (float*)d_out;

    int NB    = (N + WIN - 1) >> WSH;
    int NCBLK = (E + CEPB - 1) / CEPB;
    int NSBLK = (E + SEPB - 1) / SEPB;
    int PBLK  = (N + NT - 1) / NT;

    // ws layout: rec16[N] | pk[E + 4*NBMAX] | cnt[NB] | base[NB] | cursor[NB]
    size_t off_rec  = 0;
    size_t off_pk   = off_rec + (size_t)N * sizeof(float4);
    size_t off_cnt  = off_pk + ((size_t)E + 4 * NBMAX) * 4;
    size_t off_base = off_cnt + (size_t)NB * 4;
    size_t off_cur  = off_base + (size_t)NB * 4;
    size_t need     = off_cur + (size_t)NB * 4;

    bool ok = (ws_size >= need) && (NB <= NBMAX) && (N <= (1 << 24)) &&
              ((E & 3) == 0);

    if (!ok) {
        hipMemsetAsync(out, 0, (size_t)out_size * sizeof(float), stream);
        int grid = (E + NT - 1) / NT;
        boids_edge_kernel<<<grid, NT, 0, stream>>>(pos, vel, p_table, field,
                                                   ptype, dstI, srcI, out, E);
        return;
    }

    float4*   rec16  = (float4*)((char*)d_ws + off_rec);
    unsigned* pk     = (unsigned*)((char*)d_ws + off_pk);
    unsigned* cnt    = (unsigned*)((char*)d_ws + off_cnt);
    unsigned* basep  = (unsigned*)((char*)d_ws + off_base);
    unsigned* cursor = (unsigned*)((char*)d_ws + off_cur);

    hipMemsetAsync(out, 0, (size_t)out_size * sizeof(float), stream);
    hipMemsetAsync(cnt, 0, (size_t)NB * 4, stream);

    k_prep   <<<NCBLK + PBLK, NT, 0, stream>>>(pos, vel, field, dstI,
                                               N, E, NB, NCBLK, rec16, cnt);
    k_scanb  <<<1, NT, 0, stream>>>(cnt, basep, cursor, NB);
    k_scatter<<<NSBLK, NT, 0, stream>>>(dstI, srcI, E, NB, cursor, pk);
    dim3 agrid(NB, SPLIT);
    k_accum  <<<agrid, NT, 0, stream>>>(rec16, p_table, ptype, pk, basep, cnt,
                                        N, out);
}

// Round 15
// 122.107 us; speedup vs baseline: 1.2810x; 1.2810x over previous
//
#include <hip/hip_runtime.h>
#include <hip/hip_fp16.h>

// Boids ODE segment-sum v11: exact v9 pipeline (SEPB=8192 runs, u64 fixed-point
// accum) with k_scatter upgraded NT 256->1024: same 56KB LDS -> still 2
// blocks/CU but 32 waves/CU (was 8), per-thread chains cut 4x, write-run
// lengths and traffic unchanged. v10 lesson: smaller blocks fragment write
// runs (WRITE_SIZE +30%) — raise waves per block instead of more blocks.

#define BA1 5e-06f
#define BA2 0.0005f
#define BA3 1e-08f

#define NT 256        // threads per block (prep/scan/accum)
#define NTS 1024      // threads per scatter block
#define NWAVE 4       // NT/64
#define CEPB 4096     // edges per count block
#define SEPB 8192     // edges per scatter block (21-edge avg runs)
#define WIN 256       // receiver nodes per bucket
#define WSH 8         // log2(WIN)
#define SPLIT 8       // accum blocks per bucket
#define NBMAX 512     // max buckets
#define FPS 4194304.f // fixed-point scale 2^22

// ---------------- K1: fused pack + count ----------------
__global__ void __launch_bounds__(NT)
k_prep(const float* __restrict__ pos, const float* __restrict__ vel,
       const float* __restrict__ field, const int* __restrict__ dst,
       int N, int E, int NB, int NCBLK,
       float4* __restrict__ rec16, unsigned* __restrict__ cnt) {
    int bx = blockIdx.x, tid = threadIdx.x;
    if (bx < NCBLK) {
        __shared__ unsigned hist[NBMAX];
        for (int b = tid; b < NBMAX; b += NT) hist[b] = 0u;
        __syncthreads();
        int s = bx * CEPB, e = min(E, s + CEPB);
        int k = s + 4 * tid;
        for (; k + 3 < e; k += 4 * NT) {
            int4 d = *reinterpret_cast<const int4*>(dst + k);
            atomicAdd(&hist[d.x >> WSH], 1u);
            atomicAdd(&hist[d.y >> WSH], 1u);
            atomicAdd(&hist[d.z >> WSH], 1u);
            atomicAdd(&hist[d.w >> WSH], 1u);
        }
        int rem = (e - s) & 3;
        if (tid < rem) atomicAdd(&hist[dst[e - rem + tid] >> WSH], 1u);
        __syncthreads();
        for (int b = tid; b < NB; b += NT)
            if (hist[b]) atomicAdd(&cnt[b], hist[b]);
    } else {
        int i = (bx - NCBLK) * NT + tid;
        if (i >= N) return;
        float2 p = *reinterpret_cast<const float2*>(pos + 2 * i);
        float2 v = *reinterpret_cast<const float2*>(vel + 2 * i);
        unsigned short sx = __half_as_ushort(__float2half(v.x));
        unsigned short sy = __half_as_ushort(__float2half(v.y));
        unsigned pv = (unsigned)sx | ((unsigned)sy << 16);
        rec16[i] = make_float4(p.x, p.y, __uint_as_float(pv), field[i]);
    }
}

// ---------------- K2: single-block scan of bucket totals ----------------
__global__ void __launch_bounds__(NT)
k_scanb(const unsigned* __restrict__ cnt, unsigned* __restrict__ base,
        unsigned* __restrict__ cursor, int NB) {
    __shared__ unsigned t[NBMAX];
    __shared__ unsigned sz[NBMAX];
    int tid = threadIdx.x;
    for (int i = tid; i < NBMAX; i += NT) {
        unsigned c = (i < NB) ? cnt[i] : 0u;
        sz[i] = (c + 3u) & ~3u;
        t[i] = sz[i];
    }
    __syncthreads();
    for (int o = 1; o < NBMAX; o <<= 1) {
        unsigned v0 = (tid >= o) ? t[tid - o] : 0u;
        unsigned v1 = (tid + NT >= o) ? t[tid + NT - o] : 0u;
        __syncthreads();
        t[tid] += v0;
        t[tid + NT] += v1;
        __syncthreads();
    }
    for (int i = tid; i < NB; i += NT) {
        unsigned b = t[i] - sz[i];
        base[i] = b;
        cursor[i] = b;
    }
}

// ---------------- K3: multisplit scatter (1024 threads, 8 edges/thread) ----
__global__ void __launch_bounds__(NTS)
k_scatter(const int* __restrict__ dst, const int* __restrict__ src,
          int E, int NB,
          unsigned* __restrict__ cursor,
          unsigned* __restrict__ pk) {
    __shared__ unsigned lh[NBMAX];
    __shared__ unsigned lofs[NBMAX];
    __shared__ unsigned lcur[NBMAX];
    __shared__ unsigned gbase[NBMAX];
    __shared__ unsigned sbuf[SEPB];
    __shared__ unsigned short sbkt[SEPB];
    int blk = blockIdx.x, tid = threadIdx.x;
    int s = blk * SEPB, e = min(E, s + SEPB);

    for (int b = tid; b < NBMAX; b += NTS) lh[b] = 0u;
    __syncthreads();

    // pass 1: local histogram (8 edges/thread, 4-unrolled)
    int k = s + 4 * tid;
    for (; k + 3 < e; k += 4 * NTS) {
        int4 d = *reinterpret_cast<const int4*>(dst + k);
        atomicAdd(&lh[d.x >> WSH], 1u);
        atomicAdd(&lh[d.y >> WSH], 1u);
        atomicAdd(&lh[d.z >> WSH], 1u);
        atomicAdd(&lh[d.w >> WSH], 1u);
    }
    {
        int rem = (e - s) & 3;
        if (tid < rem) atomicAdd(&lh[dst[e - rem + tid] >> WSH], 1u);
    }
    __syncthreads();
    for (int b = tid; b < NBMAX; b += NTS) lofs[b] = lh[b];   // save counts
    __syncthreads();

    // inclusive Hillis-Steele scan over NBMAX, first 256 threads (2 elems each)
    for (int o = 1; o < NBMAX; o <<= 1) {
        unsigned v0 = 0u, v1 = 0u;
        if (tid < 256) {
            v0 = (tid >= o) ? lh[tid - o] : 0u;
            v1 = (tid + 256 >= o) ? lh[tid + 256 - o] : 0u;
        }
        __syncthreads();
        if (tid < 256) {
            lh[tid] += v0;
            lh[tid + 256] += v1;
        }
        __syncthreads();
    }
    // exclusive offsets, cursors, global reservation
    for (int b = tid; b < NBMAX; b += NTS) {
        unsigned c = lofs[b];
        unsigned ex = lh[b] - c;
        lofs[b] = ex;
        lcur[b] = ex;
        if (b < NB && c > 0u) gbase[b] = atomicAdd(&cursor[b], c);
    }
    __syncthreads();

    // pass 2: place payloads into LDS grouped by bucket
    k = s + 4 * tid;
    for (; k + 3 < e; k += 4 * NTS) {
        int4 d = *reinterpret_cast<const int4*>(dst + k);
        int4 j = *reinterpret_cast<const int4*>(src + k);
        int b0 = d.x >> WSH; unsigned r0 = atomicAdd(&lcur[b0], 1u);
        sbuf[r0] = ((unsigned)(d.x & (WIN - 1)) << 24) | (unsigned)j.x; sbkt[r0] = (unsigned short)b0;
        int b1 = d.y >> WSH; unsigned r1 = atomicAdd(&lcur[b1], 1u);
        sbuf[r1] = ((unsigned)(d.y & (WIN - 1)) << 24) | (unsigned)j.y; sbkt[r1] = (unsigned short)b1;
        int b2 = d.z >> WSH; unsigned r2 = atomicAdd(&lcur[b2], 1u);
        sbuf[r2] = ((unsigned)(d.z & (WIN - 1)) << 24) | (unsigned)j.z; sbkt[r2] = (unsigned short)b2;
        int b3 = d.w >> WSH; unsigned r3 = atomicAdd(&lcur[b3], 1u);
        sbuf[r3] = ((unsigned)(d.w & (WIN - 1)) << 24) | (unsigned)j.w; sbkt[r3] = (unsigned short)b3;
    }
    {
        int rem = (e - s) & 3;
        if (tid < rem) {
            int kk = e - rem + tid;
            int d = dst[kk];
            int b = d >> WSH; unsigned r = atomicAdd(&lcur[b], 1u);
            sbuf[r] = ((unsigned)(d & (WIN - 1)) << 24) | (unsigned)src[kk]; sbkt[r] = (unsigned short)b;
        }
    }
    __syncthreads();

    // write phase: consecutive slots in a bucket -> consecutive global addrs
    int ne = e - s;
    for (int t = tid; t < ne; t += NTS) {
        unsigned b = sbkt[t];
        pk[gbase[b] + ((unsigned)t - lofs[b])] = sbuf[t];
    }
}

// ---------------- K4: accumulate, ONE u64 integer LDS atomic per edge ----------
__global__ void __launch_bounds__(NT, 4)
k_accum(const float4* __restrict__ rec16,
        const float* __restrict__ p_table,
        const int* __restrict__ ptype,
        const unsigned* __restrict__ pk,
        const unsigned* __restrict__ base,
        const unsigned* __restrict__ cnt,
        int N,
        float* __restrict__ out) {
    __shared__ float4 wnode[WIN];                     // receiver {px,py,vx,vy}
    __shared__ float4 wcoef[WIN];                     // {c0*A1, c1*A2, c2*A3, 0}
    __shared__ unsigned long long acc64[NWAVE][WIN];  // per-wave packed {x:hi,y:lo}
    int b = blockIdx.x, tid = threadIdx.x;
    int bb = b << WSH;
    int wn = min(N - bb, WIN);
    int wv = tid >> 6;

    if (tid < wn) {
        int g = bb + tid;
        float4 r = rec16[g];
        unsigned u = __float_as_uint(r.z);
        float vx = __half2float(__ushort_as_half((unsigned short)(u & 0xFFFFu)));
        float vy = __half2float(__ushort_as_half((unsigned short)(u >> 16)));
        wnode[tid] = make_float4(r.x, r.y, vx, vy);
        int ty = ptype[g];
        wcoef[tid] = make_float4(p_table[3 * ty + 0] * BA1,
                                 p_table[3 * ty + 1] * BA2,
                                 p_table[3 * ty + 2] * BA3, 0.f);
    }
    {
        unsigned long long* a = &acc64[0][0];
        for (int t = tid; t < NWAVE * WIN; t += NT) a[t] = 0ull;
    }
    __syncthreads();

    unsigned s = base[b];
    unsigned c = cnt[b];
    unsigned e = s + c;

#define EDGE1(PV)                                                              \
    {                                                                          \
        unsigned p_ = (PV);                                                    \
        int l_ = (int)(p_ >> 24);                                              \
        int j_ = (int)(p_ & 0xFFFFFFu);                                        \
        float4 nj_ = rec16[j_];                                                \
        unsigned u_ = __float_as_uint(nj_.z);                                  \
        float vjx_ = __half2float(__ushort_as_half((unsigned short)(u_ & 0xFFFFu))); \
        float vjy_ = __half2float(__ushort_as_half((unsigned short)(u_ >> 16))); \
        float4 w_ = wnode[l_];                                                 \
        float4 c_ = wcoef[l_];                                                 \
        float dpx_ = nj_.x - w_.x, dpy_ = nj_.y - w_.y;                        \
        float dvx_ = vjx_ - w_.z, dvy_ = vjy_ - w_.w;                          \
        float d2_ = dpx_ * dpx_ + dpy_ * dpy_;                                 \
        float sd2_ = (d2_ > 0.f) ? d2_ : 1.f;                                  \
        float cdp_ = c_.x - c_.z / sd2_;                                       \
        float mx_ = (cdp_ * dpx_ + c_.y * dvx_) * nj_.w;                       \
        float my_ = (cdp_ * dpy_ + c_.y * dvy_) * nj_.w;                       \
        long long ax_ = (long long)(int)(mx_ * FPS);                           \
        long long ay_ = (long long)(int)(my_ * FPS);                           \
        atomicAdd(&acc64[wv][l_], (unsigned long long)((ax_ << 32) + ay_));    \
    }

    unsigned stride = (unsigned)NT * SPLIT * 4u;
    for (unsigned k0 = s + ((unsigned)blockIdx.y * NT + tid) * 4u;
         k0 + 4u <= e; k0 += stride) {
        uint4 a = *reinterpret_cast<const uint4*>(pk + k0);
        EDGE1(a.x); EDGE1(a.y); EDGE1(a.z); EDGE1(a.w);
    }
    unsigned tail = c & 3u;
    if (blockIdx.y == 0 && tid < (int)tail) EDGE1(pk[e - tail + tid]);
#undef EDGE1

    __syncthreads();
    // merge wave copies, decode fixed-point, accumulate into out
    for (int l = tid; l < wn; l += NT) {
        unsigned long long T = acc64[0][l] + acc64[1][l] +
                               acc64[2][l] + acc64[3][l];
        long long Ts = (long long)T;
        int yb = (int)(unsigned)(T & 0xFFFFFFFFull);   // signed lower sum
        long long rem = Ts - (long long)yb;            // exact multiple of 2^32
        int xb = (int)(rem >> 32);                     // signed upper sum
        atomicAdd(&out[2 * (bb + l) + 0], (float)xb * (1.f / FPS));
        atomicAdd(&out[2 * (bb + l) + 1], (float)yb * (1.f / FPS));
    }
}

// ---------------- fallback: baseline edge-parallel atomics ----------------
__global__ void boids_edge_kernel(const float* __restrict__ pos,
                                  const float* __restrict__ vel,
                                  const float* __restrict__ p_table,
                                  const float* __restrict__ field,
                                  const int* __restrict__ ptype,
                                  const int* __restrict__ dst_idx,
                                  const int* __restrict__ src_idx,
                                  float* __restrict__ out,
                                  int n_edges) {
    int e = blockIdx.x * blockDim.x + threadIdx.x;
    if (e >= n_edges) return;
    int i = dst_idx[e], j = src_idx[e];
    float2 pi = *reinterpret_cast<const float2*>(pos + 2 * i);
    float2 pj = *reinterpret_cast<const float2*>(pos + 2 * j);
    float2 vi = *reinterpret_cast<const float2*>(vel + 2 * i);
    float2 vj = *reinterpret_cast<const float2*>(vel + 2 * j);
    float dpx = pj.x - pi.x, dpy = pj.y - pi.y;
    float dvx = vj.x - vi.x, dvy = vj.y - vi.y;
    int t = ptype[i];
    float p0 = p_table[3 * t + 0], p1 = p_table[3 * t + 1], p2 = p_table[3 * t + 2];
    float d2 = dpx * dpx + dpy * dpy;
    float sd2 = (d2 > 0.0f) ? d2 : 1.0f;
    float cdp = p0 * BA1 - p2 * BA3 / sd2;
    float cdv = p1 * BA2;
    float f = field[j];
    atomicAdd(&out[2 * i + 0], (cdp * dpx + cdv * dvx) * f);
    atomicAdd(&out[2 * i + 1], (cdp * dpy + cdv * dvy) * f);
}

extern "C" void kernel_launch(void* const* d_in, const int* in_sizes, int n_in,
                              void* d_out, int out_size, void* d_ws, size_t ws_size,
                              hipStream_t stream) {
    const float* pos     = (const float*)d_in[0];   // [N,2]
    const float* vel     = (const float*)d_in[1];   // [N,2]
    const float* p_table = (const float*)d_in[2];   // [16,3]
    const float* field   = (const float*)d_in[3];   // [N,1]
    const int*   ptype   = (const int*)d_in[4];     // [N]
    const int*   eidx    = (const int*)d_in[5];     // [2,E]

    int N = in_sizes[0] / 2;
    int E = in_sizes[5] / 2;
    const int* dstI = eidx;
    const int* srcI = eidx + E;
    float* out = (float*)d_out;

    int NB    = (N + WIN - 1) >> WSH;
    int NCBLK = (E + CEPB - 1) / CEPB;
    int NSBLK = (E + SEPB - 1) / SEPB;
    int PBLK  = (N + NT - 1) / NT;

    // ws layout: rec16[N] | pk[E + 4*NBMAX] | cnt[NB] | base[NB] | cursor[NB]
    size_t off_rec  = 0;
    size_t off_pk   = off_rec + (size_t)N * sizeof(float4);
    size_t off_cnt  = off_pk + ((size_t)E + 4 * NBMAX) * 4;
    size_t off_base = off_cnt + (size_t)NB * 4;
    size_t off_cur  = off_base + (size_t)NB * 4;
    size_t need     = off_cur + (size_t)NB * 4;

    bool ok = (ws_size >= need) && (NB <= NBMAX) && (N <= (1 << 24)) &&
              ((E & 3) == 0);

    if (!ok) {
        hipMemsetAsync(out, 0, (size_t)out_size * sizeof(float), stream);
        int grid = (E + NT - 1) / NT;
        boids_edge_kernel<<<grid, NT, 0, stream>>>(pos, vel, p_table, field,
                                                   ptype, dstI, srcI, out, E);
        return;
    }

    float4*   rec16  = (float4*)((char*)d_ws + off_rec);
    unsigned* pk     = (unsigned*)((char*)d_ws + off_pk);
    unsigned* cnt    = (unsigned*)((char*)d_ws + off_cnt);
    unsigned* basep  = (unsigned*)((char*)d_ws + off_base);
    unsigned* cursor = (unsigned*)((char*)d_ws + off_cur);

    hipMemsetAsync(out, 0, (size_t)out_size * sizeof(float), stream);
    hipMemsetAsync(cnt, 0, (size_t)NB * 4, stream);

    k_prep   <<<NCBLK + PBLK, NT, 0, stream>>>(pos, vel, field, dstI,
                                               N, E, NB, NCBLK, rec16, cnt);
    k_scanb  <<<1, NT, 0, stream>>>(cnt, basep, cursor, NB);
    k_scatter<<<NSBLK, NTS, 0, stream>>>(dstI, srcI, E, NB, cursor, pk);
    dim3 agrid(NB, SPLIT);
    k_accum  <<<agrid, NT, 0, stream>>>(rec16, p_table, ptype, pk, basep, cnt,
                                        N, out);
}

// Round 16
// 79.884 us; speedup vs baseline: 1.9581x; 1.5285x over previous
//
#include <hip/hip_runtime.h>
#include <hip/hip_fp16.h>

// Boids ODE segment-sum v12: v11 (1024-thread multisplit scatter, u64
// fixed-point accum) with the global count pass + scan ELIMINATED via
// fixed-capacity bucket regions: bucket b owns pk[b*CAP,(b+1)*CAP), scatter
// blocks reserve runs via atomicAdd on cursor[b] (init b*CAP). CAP=28672 =
// mean load 16368 + 96 sigma (overflow impossible; clamped for safety).
// ws need 46.5MB; ws >= 53.7MB proven by round-2 run.

#define BA1 5e-06f
#define BA2 0.0005f
#define BA3 1e-08f

#define NT 256        // threads per block (pack/accum)
#define NTS 1024      // threads per scatter block
#define NWAVE 4       // NT/64
#define SEPB 8192     // edges per scatter block (21-edge avg runs)
#define WIN 256       // receiver nodes per bucket
#define WSH 8         // log2(WIN)
#define SPLIT 8       // accum blocks per bucket
#define NBMAX 512     // max buckets
#define CAP 28672u    // per-bucket region capacity (multiple of 4)
#define FPS 4194304.f // fixed-point scale 2^22

// ---------------- K1: pack records + init cursors ----------------
// rec16[i] = {pos.x, pos.y, bitcast(f16(vel.x)|f16(vel.y)<<16), field}
__global__ void __launch_bounds__(NT)
k_pack(const float* __restrict__ pos, const float* __restrict__ vel,
       const float* __restrict__ field,
       int N, int NB, int PBLK,
       float4* __restrict__ rec16, unsigned* __restrict__ cursor) {
    int bx = blockIdx.x, tid = threadIdx.x;
    if (bx == PBLK) {
        for (int b = tid; b < NB; b += NT) cursor[b] = (unsigned)b * CAP;
        return;
    }
    int i = bx * NT + tid;
    if (i >= N) return;
    float2 p = *reinterpret_cast<const float2*>(pos + 2 * i);
    float2 v = *reinterpret_cast<const float2*>(vel + 2 * i);
    unsigned short sx = __half_as_ushort(__float2half(v.x));
    unsigned short sy = __half_as_ushort(__float2half(v.y));
    unsigned pv = (unsigned)sx | ((unsigned)sy << 16);
    rec16[i] = make_float4(p.x, p.y, __uint_as_float(pv), field[i]);
}

// ---------------- K2: multisplit scatter (1024 threads, 8 edges/thread) ----
__global__ void __launch_bounds__(NTS)
k_scatter(const int* __restrict__ dst, const int* __restrict__ src,
          int E, int NB,
          unsigned* __restrict__ cursor,
          unsigned* __restrict__ pk) {
    __shared__ unsigned lh[NBMAX];
    __shared__ unsigned lofs[NBMAX];
    __shared__ unsigned lcur[NBMAX];
    __shared__ unsigned gbase[NBMAX];
    __shared__ unsigned sbuf[SEPB];
    __shared__ unsigned short sbkt[SEPB];
    int blk = blockIdx.x, tid = threadIdx.x;
    int s = blk * SEPB, e = min(E, s + SEPB);

    for (int b = tid; b < NBMAX; b += NTS) lh[b] = 0u;
    __syncthreads();

    // pass 1: local histogram (8 edges/thread, 4-unrolled)
    int k = s + 4 * tid;
    for (; k + 3 < e; k += 4 * NTS) {
        int4 d = *reinterpret_cast<const int4*>(dst + k);
        atomicAdd(&lh[d.x >> WSH], 1u);
        atomicAdd(&lh[d.y >> WSH], 1u);
        atomicAdd(&lh[d.z >> WSH], 1u);
        atomicAdd(&lh[d.w >> WSH], 1u);
    }
    {
        int rem = (e - s) & 3;
        if (tid < rem) atomicAdd(&lh[dst[e - rem + tid] >> WSH], 1u);
    }
    __syncthreads();
    for (int b = tid; b < NBMAX; b += NTS) lofs[b] = lh[b];   // save counts
    __syncthreads();

    // inclusive Hillis-Steele scan over NBMAX, first 256 threads (2 elems each)
    for (int o = 1; o < NBMAX; o <<= 1) {
        unsigned v0 = 0u, v1 = 0u;
        if (tid < 256) {
            v0 = (tid >= o) ? lh[tid - o] : 0u;
            v1 = (tid + 256 >= o) ? lh[tid + 256 - o] : 0u;
        }
        __syncthreads();
        if (tid < 256) {
            lh[tid] += v0;
            lh[tid + 256] += v1;
        }
        __syncthreads();
    }
    // exclusive offsets, cursors, global reservation
    for (int b = tid; b < NBMAX; b += NTS) {
        unsigned c = lofs[b];
        unsigned ex = lh[b] - c;
        lofs[b] = ex;
        lcur[b] = ex;
        if (b < NB && c > 0u) gbase[b] = atomicAdd(&cursor[b], c);
    }
    __syncthreads();

    // pass 2: place payloads into LDS grouped by bucket
    k = s + 4 * tid;
    for (; k + 3 < e; k += 4 * NTS) {
        int4 d = *reinterpret_cast<const int4*>(dst + k);
        int4 j = *reinterpret_cast<const int4*>(src + k);
        int b0 = d.x >> WSH; unsigned r0 = atomicAdd(&lcur[b0], 1u);
        sbuf[r0] = ((unsigned)(d.x & (WIN - 1)) << 24) | (unsigned)j.x; sbkt[r0] = (unsigned short)b0;
        int b1 = d.y >> WSH; unsigned r1 = atomicAdd(&lcur[b1], 1u);
        sbuf[r1] = ((unsigned)(d.y & (WIN - 1)) << 24) | (unsigned)j.y; sbkt[r1] = (unsigned short)b1;
        int b2 = d.z >> WSH; unsigned r2 = atomicAdd(&lcur[b2], 1u);
        sbuf[r2] = ((unsigned)(d.z & (WIN - 1)) << 24) | (unsigned)j.z; sbkt[r2] = (unsigned short)b2;
        int b3 = d.w >> WSH; unsigned r3 = atomicAdd(&lcur[b3], 1u);
        sbuf[r3] = ((unsigned)(d.w & (WIN - 1)) << 24) | (unsigned)j.w; sbkt[r3] = (unsigned short)b3;
    }
    {
        int rem = (e - s) & 3;
        if (tid < rem) {
            int kk = e - rem + tid;
            int d = dst[kk];
            int b = d >> WSH; unsigned r = atomicAdd(&lcur[b], 1u);
            sbuf[r] = ((unsigned)(d & (WIN - 1)) << 24) | (unsigned)src[kk]; sbkt[r] = (unsigned short)b;
        }
    }
    __syncthreads();

    // write phase: consecutive slots in a bucket -> consecutive global addrs
    int ne = e - s;
    for (int t = tid; t < ne; t += NTS) {
        unsigned b = sbkt[t];
        unsigned idx = gbase[b] + ((unsigned)t - lofs[b]);
        if (idx < (b + 1u) * CAP)      // safety clamp; never hit statistically
            pk[idx] = sbuf[t];
    }
}

// ---------------- K3: accumulate, ONE u64 integer LDS atomic per edge ----------
__global__ void __launch_bounds__(NT, 4)
k_accum(const float4* __restrict__ rec16,
        const float* __restrict__ p_table,
        const int* __restrict__ ptype,
        const unsigned* __restrict__ pk,
        const unsigned* __restrict__ cursor,
        int N,
        float* __restrict__ out) {
    __shared__ float4 wnode[WIN];                     // receiver {px,py,vx,vy}
    __shared__ float4 wcoef[WIN];                     // {c0*A1, c1*A2, c2*A3, 0}
    __shared__ unsigned long long acc64[NWAVE][WIN];  // per-wave packed {x:hi,y:lo}
    int b = blockIdx.x, tid = threadIdx.x;
    int bb = b << WSH;
    int wn = min(N - bb, WIN);
    int wv = tid >> 6;

    if (tid < wn) {
        int g = bb + tid;
        float4 r = rec16[g];
        unsigned u = __float_as_uint(r.z);
        float vx = __half2float(__ushort_as_half((unsigned short)(u & 0xFFFFu)));
        float vy = __half2float(__ushort_as_half((unsigned short)(u >> 16)));
        wnode[tid] = make_float4(r.x, r.y, vx, vy);
        int ty = ptype[g];
        wcoef[tid] = make_float4(p_table[3 * ty + 0] * BA1,
                                 p_table[3 * ty + 1] * BA2,
                                 p_table[3 * ty + 2] * BA3, 0.f);
    }
    {
        unsigned long long* a = &acc64[0][0];
        for (int t = tid; t < NWAVE * WIN; t += NT) a[t] = 0ull;
    }
    __syncthreads();

    unsigned s = (unsigned)b * CAP;
    unsigned c = cursor[b] - s;
    c = (c > CAP) ? CAP : c;
    unsigned e = s + c;

#define EDGE1(PV)                                                              \
    {                                                                          \
        unsigned p_ = (PV);                                                    \
        int l_ = (int)(p_ >> 24);                                              \
        int j_ = (int)(p_ & 0xFFFFFFu);                                        \
        float4 nj_ = rec16[j_];                                                \
        unsigned u_ = __float_as_uint(nj_.z);                                  \
        float vjx_ = __half2float(__ushort_as_half((unsigned short)(u_ & 0xFFFFu))); \
        float vjy_ = __half2float(__ushort_as_half((unsigned short)(u_ >> 16))); \
        float4 w_ = wnode[l_];                                                 \
        float4 c_ = wcoef[l_];                                                 \
        float dpx_ = nj_.x - w_.x, dpy_ = nj_.y - w_.y;                        \
        float dvx_ = vjx_ - w_.z, dvy_ = vjy_ - w_.w;                          \
        float d2_ = dpx_ * dpx_ + dpy_ * dpy_;                                 \
        float sd2_ = (d2_ > 0.f) ? d2_ : 1.f;                                  \
        float cdp_ = c_.x - c_.z / sd2_;                                       \
        float mx_ = (cdp_ * dpx_ + c_.y * dvx_) * nj_.w;                       \
        float my_ = (cdp_ * dpy_ + c_.y * dvy_) * nj_.w;                       \
        long long ax_ = (long long)(int)(mx_ * FPS);                           \
        long long ay_ = (long long)(int)(my_ * FPS);                           \
        atomicAdd(&acc64[wv][l_], (unsigned long long)((ax_ << 32) + ay_));    \
    }

    unsigned stride = (unsigned)NT * SPLIT * 4u;
    for (unsigned k0 = s + ((unsigned)blockIdx.y * NT + tid) * 4u;
         k0 + 4u <= e; k0 += stride) {
        uint4 a = *reinterpret_cast<const uint4*>(pk + k0);
        EDGE1(a.x); EDGE1(a.y); EDGE1(a.z); EDGE1(a.w);
    }
    unsigned tail = c & 3u;
    if (blockIdx.y == 0 && tid < (int)tail) EDGE1(pk[e - tail + tid]);
#undef EDGE1

    __syncthreads();
    // merge wave copies, decode fixed-point, accumulate into out
    for (int l = tid; l < wn; l += NT) {
        unsigned long long T = acc64[0][l] + acc64[1][l] +
                               acc64[2][l] + acc64[3][l];
        long long Ts = (long long)T;
        int yb = (int)(unsigned)(T & 0xFFFFFFFFull);   // signed lower sum
        long long rem = Ts - (long long)yb;            // exact multiple of 2^32
        int xb = (int)(rem >> 32);                     // signed upper sum
        atomicAdd(&out[2 * (bb + l) + 0], (float)xb * (1.f / FPS));
        atomicAdd(&out[2 * (bb + l) + 1], (float)yb * (1.f / FPS));
    }
}

// ---------------- fallback: baseline edge-parallel atomics ----------------
__global__ void boids_edge_kernel(const float* __restrict__ pos,
                                  const float* __restrict__ vel,
                                  const float* __restrict__ p_table,
                                  const float* __restrict__ field,
                                  const int* __restrict__ ptype,
                                  const int* __restrict__ dst_idx,
                                  const int* __restrict__ src_idx,
                                  float* __restrict__ out,
                                  int n_edges) {
    int e = blockIdx.x * blockDim.x + threadIdx.x;
    if (e >= n_edges) return;
    int i = dst_idx[e], j = src_idx[e];
    float2 pi = *reinterpret_cast<const float2*>(pos + 2 * i);
    float2 pj = *reinterpret_cast<const float2*>(pos + 2 * j);
    float2 vi = *reinterpret_cast<const float2*>(vel + 2 * i);
    float2 vj = *reinterpret_cast<const float2*>(vel + 2 * j);
    float dpx = pj.x - pi.x, dpy = pj.y - pi.y;
    float dvx = vj.x - vi.x, dvy = vj.y - vi.y;
    int t = ptype[i];
    float p0 = p_table[3 * t + 0], p1 = p_table[3 * t + 1], p2 = p_table[3 * t + 2];
    float d2 = dpx * dpx + dpy * dpy;
    float sd2 = (d2 > 0.0f) ? d2 : 1.0f;
    float cdp = p0 * BA1 - p2 * BA3 / sd2;
    float cdv = p1 * BA2;
    float f = field[j];
    atomicAdd(&out[2 * i + 0], (cdp * dpx + cdv * dvx) * f);
    atomicAdd(&out[2 * i + 1], (cdp * dpy + cdv * dvy) * f);
}

extern "C" void kernel_launch(void* const* d_in, const int* in_sizes, int n_in,
                              void* d_out, int out_size, void* d_ws, size_t ws_size,
                              hipStream_t stream) {
    const float* pos     = (const float*)d_in[0];   // [N,2]
    const float* vel     = (const float*)d_in[1];   // [N,2]
    const float* p_table = (const float*)d_in[2];   // [16,3]
    const float* field   = (const float*)d_in[3];   // [N,1]
    const int*   ptype   = (const int*)d_in[4];     // [N]
    const int*   eidx    = (const int*)d_in[5];     // [2,E]

    int N = in_sizes[0] / 2;
    int E = in_sizes[5] / 2;
    const int* dstI = eidx;
    const int* srcI = eidx + E;
    float* out = (float*)d_out;

    int NB    = (N + WIN - 1) >> WSH;
    int NSBLK = (E + SEPB - 1) / SEPB;
    int PBLK  = (N + NT - 1) / NT;

    // ws layout: rec16[N] float4 | pk[NB*CAP] u32 | cursor[NB] u32
    size_t off_rec = 0;
    size_t off_pk  = off_rec + (size_t)N * sizeof(float4);
    size_t off_cur = off_pk + (size_t)NB * CAP * 4;
    size_t need    = off_cur + (size_t)NB * 4;

    bool ok = (ws_size >= need) && (NB <= NBMAX) && (N <= (1 << 24)) &&
              ((E & 3) == 0) &&
              ((size_t)(E / (NB > 0 ? NB : 1)) * 3 / 2 + 64 <= CAP);

    if (!ok) {
        hipMemsetAsync(out, 0, (size_t)out_size * sizeof(float), stream);
        int grid = (E + NT - 1) / NT;
        boids_edge_kernel<<<grid, NT, 0, stream>>>(pos, vel, p_table, field,
                                                   ptype, dstI, srcI, out, E);
        return;
    }

    float4*   rec16  = (float4*)((char*)d_ws + off_rec);
    unsigned* pk     = (unsigned*)((char*)d_ws + off_pk);
    unsigned* cursor = (unsigned*)((char*)d_ws + off_cur);

    hipMemsetAsync(out, 0, (size_t)out_size * sizeof(float), stream);

    k_pack   <<<PBLK + 1, NT, 0, stream>>>(pos, vel, field, N, NB, PBLK,
                                           rec16, cursor);
    k_scatter<<<NSBLK, NTS, 0, stream>>>(dstI, srcI, E, NB, cursor, pk);
    dim3 agrid(NB, SPLIT);
    k_accum  <<<agrid, NT, 0, stream>>>(rec16, p_table, ptype, pk, cursor,
                                        N, out);
}